// Round 14
// baseline (116.870 us; speedup 1.0000x reference)
//
#include <hip/hip_runtime.h>
#include <stdint.h>
#include <stddef.h>

// MultiHeadAttention: B=2, S=2048, D=1024, H=16, Dh=64
// Round 14:
//   cvt6 : fp32->bf16 pre-convert (unchanged)
//   proj3: 128^2 3-slot single-barrier GEMM with UNIT-INTERLEAVED LDS layout:
//          group (16 rows x 32 cols = 1KB) stored in fragment-unit order so a
//          fragment read is base + lane*16B (conflict-free); global source
//          pre-permuted (lane -> row base+(l&15), chunk l>>4), dest linear.
//          Fixes the 8-way ds_read_b128 bank conflict that pinned proj3 at
//          ~52us across R11-R13.
//   attn : R10 verbatim.

#define NH  16
#define DH  64
#define SEQ 2048
#define DM  1024
#define NB  2

#define ACT_N (NB * SEQ * DM)   // 4194304
#define W_N   (DM * DM)         // 1048576
#define QSCALE 0.18033688011116012f   // log2(e)/sqrt(64)

typedef float  f32x4  __attribute__((ext_vector_type(4)));
typedef __bf16 bf16x8 __attribute__((ext_vector_type(8)));
typedef __bf16 bf16x4 __attribute__((ext_vector_type(4)));

__device__ __forceinline__ __bf16 f2bf(float f) { return (__bf16)f; }

__device__ __forceinline__ float fexp2(float x) {
    float r; asm("v_exp_f32 %0, %1" : "=v"(r) : "v"(x)); return r;
}

__device__ __forceinline__ void gload_lds16(const void* g, void* l) {
    __builtin_amdgcn_global_load_lds(
        (const __attribute__((address_space(1))) void*)g,
        (__attribute__((address_space(3))) void*)l, 16, 0, 0);
}

// ---------------------------------------------------------------------------
__global__ __launch_bounds__(256) void cvt6(
    const float* __restrict__ s0, const float* __restrict__ s1,
    const float* __restrict__ s2, const float* __restrict__ s3,
    const float* __restrict__ s4, const float* __restrict__ s5,
    __bf16* __restrict__ d0, __bf16* __restrict__ d1, __bf16* __restrict__ d2,
    __bf16* __restrict__ d3, __bf16* __restrict__ d4, __bf16* __restrict__ d5)
{
    const float* s; __bf16* d; int n;
    switch (blockIdx.z) {
        case 0: s = s0; d = d0; n = ACT_N; break;
        case 1: s = s1; d = d1; n = ACT_N; break;
        case 2: s = s2; d = d2; n = ACT_N; break;
        case 3: s = s3; d = d3; n = W_N;   break;
        case 4: s = s4; d = d4; n = W_N;   break;
        default: s = s5; d = d5; n = W_N;  break;
    }
    const size_t i = ((size_t)blockIdx.x * 256 + threadIdx.x) * 8;
    if (i >= (size_t)n) return;
    float4 f0 = *(const float4*)(s + i);
    float4 f1 = *(const float4*)(s + i + 4);
    bf16x8 o;
    o[0] = f2bf(f0.x); o[1] = f2bf(f0.y); o[2] = f2bf(f0.z); o[3] = f2bf(f0.w);
    o[4] = f2bf(f1.x); o[5] = f2bf(f1.y); o[6] = f2bf(f1.z); o[7] = f2bf(f1.w);
    *(bf16x8*)(d + i) = o;
}

// ---------------------------------------------------------------------------
// proj3: NT GEMM, 128x128 tile, BK=32, 3-slot pipeline, unit-interleaved LDS.
// Group g (rows 16g..16g+15, all 32 cols) lives at sX[sl][g*512 .. +512);
// unit (r = row&15, c = k-chunk) at elem offset g*512 + (c*16 + r)*8.
// Fragment read: lane L -> unit L of group -> &sX[sl][g*512 + L*8].
// z==0: Q [bh][s][dh] scaled (swapped mfma); z==1: K same; z==2: V [bh][dh][s].
// ---------------------------------------------------------------------------
__global__ __launch_bounds__(256) void proj3(
    const __bf16* __restrict__ X0, const __bf16* __restrict__ X1, const __bf16* __restrict__ X2,
    const __bf16* __restrict__ W0, const __bf16* __restrict__ W1, const __bf16* __restrict__ W2,
    const float* __restrict__ b0, const float* __restrict__ b1, const float* __restrict__ b2,
    __bf16* __restrict__ dq, __bf16* __restrict__ dk, __bf16* __restrict__ dv)
{
    __shared__ __align__(16) __bf16 sA[3][4096];   // 8 KB/slot, 8 groups
    __shared__ __align__(16) __bf16 sB[3][4096];

    const __bf16 *X, *W; const float* bias; __bf16* dst;
    if (blockIdx.z == 0)      { X = X0; W = W0; bias = b0; dst = dq; }
    else if (blockIdx.z == 1) { X = X1; W = W1; bias = b1; dst = dk; }
    else                      { X = X2; W = W2; bias = b2; dst = dv; }
    const bool vpath = (blockIdx.z == 2);

    const int lane = threadIdx.x & 63;
    const int wv   = threadIdx.x >> 6;
    const int mb = blockIdx.x * 128;
    const int nb = blockIdx.y * 128;
    const int lm0 = (wv >> 1) * 64;
    const int ln0 = (wv & 1) * 64;
    const int lr = lane & 15;
    const int lg = lane >> 4;

    // staging source: lane -> (row = +lr, k-chunk = lg). Wave wv stages
    // groups 2wv (rows 32wv..+16) and 2wv+1 (rows +16..+32) of A and B.
    const __bf16* xs = X + (size_t)(mb + wv * 32 + lr) * DM + lg * 8;
    const __bf16* ws = W + (size_t)(nb + wv * 32 + lr) * DM + lg * 8;

#define PSTAGE(SL, T) { \
    gload_lds16(xs + (size_t)(T) * 32,                   &sA[SL][(wv * 2)     * 512]); \
    gload_lds16(xs + (size_t)(T) * 32 + (size_t)16 * DM, &sA[SL][(wv * 2 + 1) * 512]); \
    gload_lds16(ws + (size_t)(T) * 32,                   &sB[SL][(wv * 2)     * 512]); \
    gload_lds16(ws + (size_t)(T) * 32 + (size_t)16 * DM, &sB[SL][(wv * 2 + 1) * 512]); }

    const int gA0 = lm0 >> 4;    // wave's first A group (0 or 4)
    const int gB0 = ln0 >> 4;    // wave's first B group (0 or 4)

    f32x4 acc[4][4];
#pragma unroll
    for (int i = 0; i < 4; ++i)
#pragma unroll
        for (int j = 0; j < 4; ++j) acc[i][j] = (f32x4){0.f, 0.f, 0.f, 0.f};

    PSTAGE(0, 0);
    PSTAGE(1, 1);

#pragma unroll
    for (int t = 0; t < 32; ++t) {       // full unroll: slots & guards constant
        __syncthreads();
        if (t + 2 < 32) PSTAGE((t + 2) % 3, t + 2);

        const int sl = t % 3;
        bf16x8 a[4], b[4];
#pragma unroll
        for (int f = 0; f < 4; ++f) {
            a[f] = *(const bf16x8*)&sA[sl][(gA0 + f) * 512 + lane * 8];
            b[f] = *(const bf16x8*)&sB[sl][(gB0 + f) * 512 + lane * 8];
        }
        __builtin_amdgcn_s_setprio(1);
        if (!vpath) {
            // D^T: rows = n, cols = m -> acc[nt][mt]
#pragma unroll
            for (int nt = 0; nt < 4; ++nt)
#pragma unroll
                for (int mt = 0; mt < 4; ++mt)
                    acc[nt][mt] = __builtin_amdgcn_mfma_f32_16x16x32_bf16(
                        b[nt], a[mt], acc[nt][mt], 0, 0, 0);
        } else {
            // D: rows = m, cols = n -> acc[mt][nt]
#pragma unroll
            for (int mt = 0; mt < 4; ++mt)
#pragma unroll
                for (int nt = 0; nt < 4; ++nt)
                    acc[mt][nt] = __builtin_amdgcn_mfma_f32_16x16x32_bf16(
                        a[mt], b[nt], acc[mt][nt], 0, 0, 0);
        }
        __builtin_amdgcn_s_setprio(0);
    }
#undef PSTAGE

    if (!vpath) {
        // lane: n = nb+ln0+nt*16+lg*4 (+4 consecutive dh), m = mb+lm0+mt*16+lr
        const float scale = (blockIdx.z == 0) ? QSCALE : 1.0f;
#pragma unroll
        for (int nt = 0; nt < 4; ++nt) {
            const int n_base = nb + ln0 + nt * 16 + lg * 4;
            const float4 bb = *(const float4*)&bias[n_base];
            const int h = n_base >> 6, dh = n_base & 63;
#pragma unroll
            for (int mt = 0; mt < 4; ++mt) {
                const int m_g = mb + lm0 + mt * 16 + lr;
                const int bi = m_g >> 11;
                const int s  = m_g & (SEQ - 1);
                bf16x4 w;
                w[0] = f2bf((acc[nt][mt][0] + bb.x) * scale);
                w[1] = f2bf((acc[nt][mt][1] + bb.y) * scale);
                w[2] = f2bf((acc[nt][mt][2] + bb.z) * scale);
                w[3] = f2bf((acc[nt][mt][3] + bb.w) * scale);
                *(bf16x4*)&dst[((size_t)((bi * NH + h) * SEQ + s)) * DH + dh] = w;
            }
        }
    } else {
        // lane: m = mb+lm0+mt*16+lg*4 (+4 consecutive s), n = nb+ln0+nt*16+lr
        const int h = (nb + ln0) >> 6;
#pragma unroll
        for (int nt = 0; nt < 4; ++nt) {
            const int n_g = nb + ln0 + nt * 16 + lr;
            const float bb = bias[n_g];
            const int dh = n_g & 63;
#pragma unroll
            for (int mt = 0; mt < 4; ++mt) {
                const int m_g = mb + lm0 + mt * 16 + lg * 4;
                const int bi = m_g >> 11;
                const int s0 = m_g & (SEQ - 1);
                bf16x4 w;
#pragma unroll
                for (int r = 0; r < 4; ++r) w[r] = f2bf(acc[mt][nt][r] + bb);
                *(bf16x4*)&dst[((size_t)((bi * NH + h) * DH + dh)) * SEQ + s0] = w;
            }
        }
    }
}

// ---------------------------------------------------------------------------
// Unnormalized streaming attention, register P, l via ones-MFMA, FULL UNROLL.
// Per tile: SMAX(t) | barrier | STAGE(t+2) ; QK(t+1) ; PV(t).  (R10 verbatim)
// ---------------------------------------------------------------------------
__global__ __launch_bounds__(256) void attn_kernel(
    const __bf16* __restrict__ qh, const __bf16* __restrict__ kh,
    const __bf16* __restrict__ vT, float* __restrict__ out)
{
    __shared__ __align__(16) __bf16 kbuf[3][4096];   // 24 KB  [key][d] swizzled
    __shared__ __align__(16) __bf16 vbuf[3][4096];   // 24 KB  [d][key] swizzled

    const int tid  = threadIdx.x;
    const int lane = tid & 63;
    const int wv   = tid >> 6;
    const int i    = blockIdx.x;
    const int slot = i >> 3;
    const int bh   = (i & 7) * 4 + (slot >> 4);   // XCD x owns heads 4x..4x+3
    const int qt   = slot & 15;
    const size_t hb = (size_t)bh * SEQ * DH;
    const int q0 = qt * 128 + wv * 32;
    const int lq = lane & 15;
    const int lg = lane >> 4;
    const int swz = (lq & 7) << 4;

    const int p0 = tid, p1 = tid + 256;
    const int c0 = (p0 ^ ((p0 >> 3) & 7)) & 7;
    const int c1 = (p1 ^ ((p1 >> 3) & 7)) & 7;
    const int r0 = p0 >> 3, r1 = p1 >> 3;
    const int gr0 = (r0 & 35) | ((r0 & 12) << 1) | ((r0 & 16) >> 2);  // g(r0)
    const int gr1 = (r1 & 35) | ((r1 & 12) << 1) | ((r1 & 16) >> 2);  // g(r1)
    const __bf16* ks0 = kh + hb + (size_t)gr0 * DH + c0 * 8;
    const __bf16* ks1 = kh + hb + (size_t)gr1 * DH + c1 * 8;
    const __bf16* vs0 = vT + hb + (size_t)r0 * SEQ + c0 * 8;
    const __bf16* vs1 = vT + hb + (size_t)r1 * SEQ + c1 * 8;
    const int dst0 = wv * 512;
    const int dst1 = 2048 + wv * 512;

#define STAGE(SEL, TI) { \
    gload_lds16(ks0 + (size_t)(TI) * 64 * DH, &kbuf[SEL][dst0]); \
    gload_lds16(ks1 + (size_t)(TI) * 64 * DH, &kbuf[SEL][dst1]); \
    gload_lds16(vs0 + (TI) * 64, &vbuf[SEL][dst0]); \
    gload_lds16(vs1 + (TI) * 64, &vbuf[SEL][dst1]); }

    bf16x8 bQ[2][2];
#pragma unroll
    for (int qtf = 0; qtf < 2; ++qtf)
#pragma unroll
        for (int ks = 0; ks < 2; ++ks)
            bQ[qtf][ks] = *(const bf16x8*)(qh + hb +
                (size_t)(q0 + qtf * 16 + lq) * DH + ks * 32 + lg * 8);

    bf16x8 ONES;
#pragma unroll
    for (int e = 0; e < 8; ++e) ONES[e] = f2bf(1.0f);

    f32x4 O[2][4];
#pragma unroll
    for (int qtf = 0; qtf < 2; ++qtf)
#pragma unroll
        for (int dt = 0; dt < 4; ++dt) O[qtf][dt] = (f32x4){0.f, 0.f, 0.f, 0.f};
    f32x4 Ol[2];
    Ol[0] = (f32x4){0.f, 0.f, 0.f, 0.f};
    Ol[1] = (f32x4){0.f, 0.f, 0.f, 0.f};

    const int rdk0 = lq * 128 + ((0 * 64 + lg * 16) ^ swz);
    const int rdk1 = lq * 128 + ((1 * 64 + lg * 16) ^ swz);

    f32x4 scA[2][4], scB[2][4];
    bf16x8 paf[2][2];

#define QK(SL, SC) { \
    const char* kc = (const char*)&kbuf[SL][0]; \
    _Pragma("unroll") for (int kt = 0; kt < 4; ++kt) { \
        const bf16x8 ak0 = *(const bf16x8*)(kc + kt * 2048 + rdk0); \
        const bf16x8 ak1 = *(const bf16x8*)(kc + kt * 2048 + rdk1); \
        _Pragma("unroll") for (int qtf = 0; qtf < 2; ++qtf) { \
            f32x4 c = (f32x4){0.f, 0.f, 0.f, 0.f}; \
            c = __builtin_amdgcn_mfma_f32_16x16x32_bf16(ak0, bQ[qtf][0], c, 0, 0, 0); \
            c = __builtin_amdgcn_mfma_f32_16x16x32_bf16(ak1, bQ[qtf][1], c, 0, 0, 0); \
            SC[qtf][kt] = c; } } }

#define SMAX(SC) { \
    _Pragma("unroll") for (int qtf = 0; qtf < 2; ++qtf) \
    _Pragma("unroll") for (int ks = 0; ks < 2; ++ks) { \
        bf16x8 w; \
        _Pragma("unroll") for (int r = 0; r < 4; ++r) { \
            w[r]     = f2bf(fexp2(SC[qtf][2 * ks][r])); \
            w[4 + r] = f2bf(fexp2(SC[qtf][2 * ks + 1][r])); } \
        paf[qtf][ks] = w; } }

#define PV(SL) { \
    const char* vc = (const char*)&vbuf[SL][0]; \
    _Pragma("unroll") for (int ks = 0; ks < 2; ++ks) { \
        const int rd = (ks == 0) ? rdk0 : rdk1; \
        _Pragma("unroll") for (int dt = 0; dt < 4; ++dt) { \
            const bf16x8 bv = *(const bf16x8*)(vc + dt * 2048 + rd); \
            O[0][dt] = __builtin_amdgcn_mfma_f32_16x16x32_bf16(paf[0][ks], bv, O[0][dt], 0, 0, 0); \
            O[1][dt] = __builtin_amdgcn_mfma_f32_16x16x32_bf16(paf[1][ks], bv, O[1][dt], 0, 0, 0); } \
        Ol[0] = __builtin_amdgcn_mfma_f32_16x16x32_bf16(paf[0][ks], ONES, Ol[0], 0, 0, 0); \
        Ol[1] = __builtin_amdgcn_mfma_f32_16x16x32_bf16(paf[1][ks], ONES, Ol[1], 0, 0, 0); } }

#define BODY(T, SCUR, SNXT) { \
    SMAX(SCUR); \
    __syncthreads(); \
    if ((T) + 2 < 32) STAGE(((T) + 2) % 3, (T) + 2); \
    __builtin_amdgcn_s_setprio(1); \
    if ((T) + 1 < 32) QK(((T) + 1) % 3, SNXT); \
    PV((T) % 3); \
    __builtin_amdgcn_s_setprio(0); }

    STAGE(0, 0);
    STAGE(1, 1);
    __syncthreads();
    QK(0, scA);

#pragma unroll
    for (int t = 0; t < 32; t += 2) {
        BODY(t, scA, scB);
        BODY(t + 1, scB, scA);
    }
#undef BODY
#undef PV
#undef SMAX
#undef QK
#undef STAGE

    const int b = bh >> 4, h = bh & 15;
#pragma unroll
    for (int qtf = 0; qtf < 2; ++qtf) {
#pragma unroll
        for (int r = 0; r < 4; ++r) {
            const float li = 1.0f / (qtf ? Ol[1][r] : Ol[0][r]);
            const int s_g = q0 + qtf * 16 + lg * 4 + r;
            float* op = out + ((size_t)(b * SEQ + s_g)) * DM + h * DH;
#pragma unroll
            for (int dt = 0; dt < 4; ++dt)
                op[dt * 16 + lq] = O[qtf][dt][r] * li;
        }
    }
}

// ---------------------------------------------------------------------------
extern "C" void kernel_launch(void* const* d_in, const int* in_sizes, int n_in,
                              void* d_out, int out_size, void* d_ws, size_t ws_size,
                              hipStream_t stream)
{
    (void)in_sizes; (void)n_in; (void)out_size; (void)ws_size;
    const float* q  = (const float*)d_in[0];
    const float* k  = (const float*)d_in[1];
    const float* v  = (const float*)d_in[2];
    const float* Wq = (const float*)d_in[3];
    const float* bq = (const float*)d_in[4];
    const float* Wk = (const float*)d_in[5];
    const float* bk = (const float*)d_in[6];
    const float* Wv = (const float*)d_in[7];
    const float* bv = (const float*)d_in[8];

    const size_t act = (size_t)ACT_N;
    const size_t wn  = (size_t)W_N;
    __bf16* qx  = (__bf16*)d_ws;
    __bf16* kx  = qx + act;
    __bf16* vx  = kx + act;
    __bf16* wqb = vx + act;
    __bf16* wkb = wqb + wn;
    __bf16* wvb = wkb + wn;
    __bf16* qhd = wvb + wn;
    __bf16* khd = qhd + act;
    __bf16* vhd = khd + act;               // vhd: [bh][64][s] transposed
    float* out = (float*)d_out;

    cvt6<<<dim3(2048, 1, 6), dim3(256), 0, stream>>>(
        q, k, v, Wq, Wk, Wv, qx, kx, vx, wqb, wkb, wvb);
    proj3<<<dim3(32, 8, 3), dim3(256), 0, stream>>>(
        qx, kx, vx, wqb, wkb, wvb, bq, bk, bv, qhd, khd, vhd);
    attn_kernel<<<dim3(512), dim3(256), 0, stream>>>(qhd, khd, vhd, out);
}

// Round 15
// 101.458 us; speedup vs baseline: 1.1519x; 1.1519x over previous
//
#include <hip/hip_runtime.h>
#include <stdint.h>
#include <stddef.h>

// MultiHeadAttention: B=2, S=2048, D=1024, H=16, Dh=64
// Round 15: counted-vmcnt pipelines (T4) — never drain vmcnt to 0 mid-loop.
//   cvt6 : unchanged
//   proj3: 3-slot, WAITVM(4)+raw s_barrier per step (slot t waited 2 iters
//          after issue); [128][32] LDS with chunk^=(row>>1)&3 swizzle
//          (write via global-source permute inside each 64B row -> coalescing
//          kept; read via XOR). R11 orientation epilogue.
//   attn : 4-slot (64KB, still 2 blocks/CU), STAGE(t+3), WAITVM(4)/(0)+raw
//          barrier. R10 register-P / ones-MFMA / full unroll kept.

#define NH  16
#define DH  64
#define SEQ 2048
#define DM  1024
#define NB  2

#define ACT_N (NB * SEQ * DM)
#define W_N   (DM * DM)
#define QSCALE 0.18033688011116012f   // log2(e)/sqrt(64)

typedef float  f32x4  __attribute__((ext_vector_type(4)));
typedef __bf16 bf16x8 __attribute__((ext_vector_type(8)));
typedef __bf16 bf16x4 __attribute__((ext_vector_type(4)));

__device__ __forceinline__ __bf16 f2bf(float f) { return (__bf16)f; }

__device__ __forceinline__ float fexp2(float x) {
    float r; asm("v_exp_f32 %0, %1" : "=v"(r) : "v"(x)); return r;
}

__device__ __forceinline__ void gload_lds16(const void* g, void* l) {
    __builtin_amdgcn_global_load_lds(
        (const __attribute__((address_space(1))) void*)g,
        (__attribute__((address_space(3))) void*)l, 16, 0, 0);
}

#define WAITVM(N) asm volatile("s_waitcnt vmcnt(" #N ")" ::: "memory")

// ---------------------------------------------------------------------------
__global__ __launch_bounds__(256) void cvt6(
    const float* __restrict__ s0, const float* __restrict__ s1,
    const float* __restrict__ s2, const float* __restrict__ s3,
    const float* __restrict__ s4, const float* __restrict__ s5,
    __bf16* __restrict__ d0, __bf16* __restrict__ d1, __bf16* __restrict__ d2,
    __bf16* __restrict__ d3, __bf16* __restrict__ d4, __bf16* __restrict__ d5)
{
    const float* s; __bf16* d; int n;
    switch (blockIdx.z) {
        case 0: s = s0; d = d0; n = ACT_N; break;
        case 1: s = s1; d = d1; n = ACT_N; break;
        case 2: s = s2; d = d2; n = ACT_N; break;
        case 3: s = s3; d = d3; n = W_N;   break;
        case 4: s = s4; d = d4; n = W_N;   break;
        default: s = s5; d = d5; n = W_N;  break;
    }
    const size_t i = ((size_t)blockIdx.x * 256 + threadIdx.x) * 8;
    if (i >= (size_t)n) return;
    float4 f0 = *(const float4*)(s + i);
    float4 f1 = *(const float4*)(s + i + 4);
    bf16x8 o;
    o[0] = f2bf(f0.x); o[1] = f2bf(f0.y); o[2] = f2bf(f0.z); o[3] = f2bf(f0.w);
    o[4] = f2bf(f1.x); o[5] = f2bf(f1.y); o[6] = f2bf(f1.z); o[7] = f2bf(f1.w);
    *(bf16x8*)(d + i) = o;
}

// ---------------------------------------------------------------------------
// proj3: NT GEMM, 128x128, BK=32, 3-slot counted-vmcnt pipeline.
// LDS [128][32] bf16; phys chunk p of row r holds global chunk p^((r>>1)&3).
// z==0: Q [bh][s][dh] scaled (swapped mfma); z==1: K same; z==2: V [bh][dh][s].
// ---------------------------------------------------------------------------
__global__ __launch_bounds__(256) void proj3(
    const __bf16* __restrict__ X0, const __bf16* __restrict__ X1, const __bf16* __restrict__ X2,
    const __bf16* __restrict__ W0, const __bf16* __restrict__ W1, const __bf16* __restrict__ W2,
    const float* __restrict__ b0, const float* __restrict__ b1, const float* __restrict__ b2,
    __bf16* __restrict__ dq, __bf16* __restrict__ dk, __bf16* __restrict__ dv)
{
    __shared__ __align__(16) __bf16 sA[3][4096];   // [128][32] per slot
    __shared__ __align__(16) __bf16 sB[3][4096];

    const __bf16 *X, *W; const float* bias; __bf16* dst;
    if (blockIdx.z == 0)      { X = X0; W = W0; bias = b0; dst = dq; }
    else if (blockIdx.z == 1) { X = X1; W = W1; bias = b1; dst = dk; }
    else                      { X = X2; W = W2; bias = b2; dst = dv; }
    const bool vpath = (blockIdx.z == 2);

    const int lane = threadIdx.x & 63;
    const int wv   = threadIdx.x >> 6;
    const int mb = blockIdx.x * 128;
    const int nb = blockIdx.y * 128;
    const int lm0 = (wv >> 1) * 64;
    const int ln0 = (wv & 1) * 64;
    const int lr = lane & 15;
    const int lg = lane >> 4;

    // staging: lane -> row srow=lane>>2 within 16-row group, phys chunk lane&3.
    // global chunk fetched = (lane&3) ^ ((srow>>1)&3) = (lane&3)^((lane>>3)&3).
    const int srow = lane >> 2;
    const int scol = (((lane & 3) ^ ((lane >> 3) & 3))) * 8;
    const __bf16* xs = X + (size_t)(mb + wv * 32 + srow) * DM + scol;
    const __bf16* ws = W + (size_t)(nb + wv * 32 + srow) * DM + scol;

#define PSTAGE(SL, T) { \
    gload_lds16(xs + (size_t)(T) * 32,                   &sA[SL][wv * 1024]); \
    gload_lds16(xs + (size_t)(T) * 32 + (size_t)16 * DM, &sA[SL][wv * 1024 + 512]); \
    gload_lds16(ws + (size_t)(T) * 32,                   &sB[SL][wv * 1024]); \
    gload_lds16(ws + (size_t)(T) * 32 + (size_t)16 * DM, &sB[SL][wv * 1024 + 512]); }

    // fragment read: row = lm0/ln0 + f*16 + lr, phys chunk = lg ^ ((lr>>1)&3)
    const int rchunk = (lg ^ ((lr >> 1) & 3)) * 8;

    f32x4 acc[4][4];
#pragma unroll
    for (int i = 0; i < 4; ++i)
#pragma unroll
        for (int j = 0; j < 4; ++j) acc[i][j] = (f32x4){0.f, 0.f, 0.f, 0.f};

    PSTAGE(0, 0);
    PSTAGE(1, 1);

#pragma unroll
    for (int t = 0; t < 32; ++t) {
        // need slot t complete; allow slot t+1 (4 loads) in flight
        if (t <= 30) { WAITVM(4); } else { WAITVM(0); }
        __builtin_amdgcn_s_barrier();
        if (t + 2 < 32) PSTAGE((t + 2) % 3, t + 2);

        const int sl = t % 3;
        bf16x8 a[4], b[4];
#pragma unroll
        for (int f = 0; f < 4; ++f) {
            a[f] = *(const bf16x8*)&sA[sl][(lm0 + f * 16 + lr) * 32 + rchunk];
            b[f] = *(const bf16x8*)&sB[sl][(ln0 + f * 16 + lr) * 32 + rchunk];
        }
        __builtin_amdgcn_s_setprio(1);
        if (!vpath) {
#pragma unroll
            for (int nt = 0; nt < 4; ++nt)
#pragma unroll
                for (int mt = 0; mt < 4; ++mt)
                    acc[nt][mt] = __builtin_amdgcn_mfma_f32_16x16x32_bf16(
                        b[nt], a[mt], acc[nt][mt], 0, 0, 0);
        } else {
#pragma unroll
            for (int mt = 0; mt < 4; ++mt)
#pragma unroll
                for (int nt = 0; nt < 4; ++nt)
                    acc[mt][nt] = __builtin_amdgcn_mfma_f32_16x16x32_bf16(
                        a[mt], b[nt], acc[mt][nt], 0, 0, 0);
        }
        __builtin_amdgcn_s_setprio(0);
    }
#undef PSTAGE

    if (!vpath) {
        const float scale = (blockIdx.z == 0) ? QSCALE : 1.0f;
#pragma unroll
        for (int nt = 0; nt < 4; ++nt) {
            const int n_base = nb + ln0 + nt * 16 + lg * 4;
            const float4 bb = *(const float4*)&bias[n_base];
            const int h = n_base >> 6, dh = n_base & 63;
#pragma unroll
            for (int mt = 0; mt < 4; ++mt) {
                const int m_g = mb + lm0 + mt * 16 + lr;
                const int bi = m_g >> 11;
                const int s  = m_g & (SEQ - 1);
                bf16x4 w;
                w[0] = f2bf((acc[nt][mt][0] + bb.x) * scale);
                w[1] = f2bf((acc[nt][mt][1] + bb.y) * scale);
                w[2] = f2bf((acc[nt][mt][2] + bb.z) * scale);
                w[3] = f2bf((acc[nt][mt][3] + bb.w) * scale);
                *(bf16x4*)&dst[((size_t)((bi * NH + h) * SEQ + s)) * DH + dh] = w;
            }
        }
    } else {
        const int h = (nb + ln0) >> 6;
#pragma unroll
        for (int nt = 0; nt < 4; ++nt) {
            const int n_g = nb + ln0 + nt * 16 + lr;
            const float bb = bias[n_g];
            const int dh = n_g & 63;
#pragma unroll
            for (int mt = 0; mt < 4; ++mt) {
                const int m_g = mb + lm0 + mt * 16 + lg * 4;
                const int bi = m_g >> 11;
                const int s0 = m_g & (SEQ - 1);
                bf16x4 w;
#pragma unroll
                for (int r = 0; r < 4; ++r) w[r] = f2bf(acc[mt][nt][r] + bb);
                *(bf16x4*)&dst[((size_t)((bi * NH + h) * DH + dh)) * SEQ + s0] = w;
            }
        }
    }
}

// ---------------------------------------------------------------------------
// Attention: register-P, ones-MFMA l, full unroll, 4-slot counted-vmcnt.
// Per tile: SMAX(t) | WAITVM | s_barrier | STAGE(t+3) ; QK(t+1) ; PV(t).
// ---------------------------------------------------------------------------
__global__ __launch_bounds__(256) void attn_kernel(
    const __bf16* __restrict__ qh, const __bf16* __restrict__ kh,
    const __bf16* __restrict__ vT, float* __restrict__ out)
{
    __shared__ __align__(16) __bf16 kbuf[4][4096];   // 32 KB
    __shared__ __align__(16) __bf16 vbuf[4][4096];   // 32 KB

    const int tid  = threadIdx.x;
    const int lane = tid & 63;
    const int wv   = tid >> 6;
    const int i    = blockIdx.x;
    const int slot = i >> 3;
    const int bh   = (i & 7) * 4 + (slot >> 4);
    const int qt   = slot & 15;
    const size_t hb = (size_t)bh * SEQ * DH;
    const int q0 = qt * 128 + wv * 32;
    const int lq = lane & 15;
    const int lg = lane >> 4;
    const int swz = (lq & 7) << 4;

    const int p0 = tid, p1 = tid + 256;
    const int c0 = (p0 ^ ((p0 >> 3) & 7)) & 7;
    const int c1 = (p1 ^ ((p1 >> 3) & 7)) & 7;
    const int r0 = p0 >> 3, r1 = p1 >> 3;
    const int gr0 = (r0 & 35) | ((r0 & 12) << 1) | ((r0 & 16) >> 2);
    const int gr1 = (r1 & 35) | ((r1 & 12) << 1) | ((r1 & 16) >> 2);
    const __bf16* ks0 = kh + hb + (size_t)gr0 * DH + c0 * 8;
    const __bf16* ks1 = kh + hb + (size_t)gr1 * DH + c1 * 8;
    const __bf16* vs0 = vT + hb + (size_t)r0 * SEQ + c0 * 8;
    const __bf16* vs1 = vT + hb + (size_t)r1 * SEQ + c1 * 8;
    const int dst0 = wv * 512;
    const int dst1 = 2048 + wv * 512;

#define STAGE(SEL, TI) { \
    gload_lds16(ks0 + (size_t)(TI) * 64 * DH, &kbuf[SEL][dst0]); \
    gload_lds16(ks1 + (size_t)(TI) * 64 * DH, &kbuf[SEL][dst1]); \
    gload_lds16(vs0 + (TI) * 64, &vbuf[SEL][dst0]); \
    gload_lds16(vs1 + (TI) * 64, &vbuf[SEL][dst1]); }

    bf16x8 bQ[2][2];
#pragma unroll
    for (int qtf = 0; qtf < 2; ++qtf)
#pragma unroll
        for (int ks = 0; ks < 2; ++ks)
            bQ[qtf][ks] = *(const bf16x8*)(qh + hb +
                (size_t)(q0 + qtf * 16 + lq) * DH + ks * 32 + lg * 8);

    bf16x8 ONES;
#pragma unroll
    for (int e = 0; e < 8; ++e) ONES[e] = f2bf(1.0f);

    f32x4 O[2][4];
#pragma unroll
    for (int qtf = 0; qtf < 2; ++qtf)
#pragma unroll
        for (int dt = 0; dt < 4; ++dt) O[qtf][dt] = (f32x4){0.f, 0.f, 0.f, 0.f};
    f32x4 Ol[2];
    Ol[0] = (f32x4){0.f, 0.f, 0.f, 0.f};
    Ol[1] = (f32x4){0.f, 0.f, 0.f, 0.f};

    const int rdk0 = lq * 128 + ((0 * 64 + lg * 16) ^ swz);
    const int rdk1 = lq * 128 + ((1 * 64 + lg * 16) ^ swz);

    f32x4 scA[2][4], scB[2][4];
    bf16x8 paf[2][2];

#define QK(SL, SC) { \
    const char* kc = (const char*)&kbuf[SL][0]; \
    _Pragma("unroll") for (int kt = 0; kt < 4; ++kt) { \
        const bf16x8 ak0 = *(const bf16x8*)(kc + kt * 2048 + rdk0); \
        const bf16x8 ak1 = *(const bf16x8*)(kc + kt * 2048 + rdk1); \
        _Pragma("unroll") for (int qtf = 0; qtf < 2; ++qtf) { \
            f32x4 c = (f32x4){0.f, 0.f, 0.f, 0.f}; \
            c = __builtin_amdgcn_mfma_f32_16x16x32_bf16(ak0, bQ[qtf][0], c, 0, 0, 0); \
            c = __builtin_amdgcn_mfma_f32_16x16x32_bf16(ak1, bQ[qtf][1], c, 0, 0, 0); \
            SC[qtf][kt] = c; } } }

#define SMAX(SC) { \
    _Pragma("unroll") for (int qtf = 0; qtf < 2; ++qtf) \
    _Pragma("unroll") for (int ks = 0; ks < 2; ++ks) { \
        bf16x8 w; \
        _Pragma("unroll") for (int r = 0; r < 4; ++r) { \
            w[r]     = f2bf(fexp2(SC[qtf][2 * ks][r])); \
            w[4 + r] = f2bf(fexp2(SC[qtf][2 * ks + 1][r])); } \
        paf[qtf][ks] = w; } }

#define PV(SL) { \
    const char* vc = (const char*)&vbuf[SL][0]; \
    _Pragma("unroll") for (int ks = 0; ks < 2; ++ks) { \
        const int rd = (ks == 0) ? rdk0 : rdk1; \
        _Pragma("unroll") for (int dt = 0; dt < 4; ++dt) { \
            const bf16x8 bv = *(const bf16x8*)(vc + dt * 2048 + rd); \
            O[0][dt] = __builtin_amdgcn_mfma_f32_16x16x32_bf16(paf[0][ks], bv, O[0][dt], 0, 0, 0); \
            O[1][dt] = __builtin_amdgcn_mfma_f32_16x16x32_bf16(paf[1][ks], bv, O[1][dt], 0, 0, 0); } \
        Ol[0] = __builtin_amdgcn_mfma_f32_16x16x32_bf16(paf[0][ks], ONES, Ol[0], 0, 0, 0); \
        Ol[1] = __builtin_amdgcn_mfma_f32_16x16x32_bf16(paf[1][ks], ONES, Ol[1], 0, 0, 0); } }

// need slot t+1 complete before QK(t+1); allow {t+2,t+3} (8) -> wait to 4.
// t=29: in-flight {30,31} -> 4. t>=30: need newest -> 0.
#define BODY(T, SCUR, SNXT) { \
    SMAX(SCUR); \
    if ((T) <= 29) { WAITVM(4); } else { WAITVM(0); } \
    __builtin_amdgcn_s_barrier(); \
    if ((T) + 3 < 32) STAGE(((T) + 3) & 3, (T) + 3); \
    __builtin_amdgcn_s_setprio(1); \
    if ((T) + 1 < 32) QK(((T) + 1) & 3, SNXT); \
    PV((T) & 3); \
    __builtin_amdgcn_s_setprio(0); }

    STAGE(0, 0);
    STAGE(1, 1);
    STAGE(2, 2);
    WAITVM(8);                      // retires bQ + slot 0 (in-order)
    __builtin_amdgcn_s_barrier();
    QK(0, scA);

#pragma unroll
    for (int t = 0; t < 32; t += 2) {
        BODY(t, scA, scB);
        BODY(t + 1, scB, scA);
    }
#undef BODY
#undef PV
#undef SMAX
#undef QK
#undef STAGE

    const int b = bh >> 4, h = bh & 15;
#pragma unroll
    for (int qtf = 0; qtf < 2; ++qtf) {
#pragma unroll
        for (int r = 0; r < 4; ++r) {
            const float li = 1.0f / (qtf ? Ol[1][r] : Ol[0][r]);
            const int s_g = q0 + qtf * 16 + lg * 4 + r;
            float* op = out + ((size_t)(b * SEQ + s_g)) * DM + h * DH;
#pragma unroll
            for (int dt = 0; dt < 4; ++dt)
                op[dt * 16 + lq] = O[qtf][dt][r] * li;
        }
    }
}

// ---------------------------------------------------------------------------
extern "C" void kernel_launch(void* const* d_in, const int* in_sizes, int n_in,
                              void* d_out, int out_size, void* d_ws, size_t ws_size,
                              hipStream_t stream)
{
    (void)in_sizes; (void)n_in; (void)out_size; (void)ws_size;
    const float* q  = (const float*)d_in[0];
    const float* k  = (const float*)d_in[1];
    const float* v  = (const float*)d_in[2];
    const float* Wq = (const float*)d_in[3];
    const float* bq = (const float*)d_in[4];
    const float* Wk = (const float*)d_in[5];
    const float* bk = (const float*)d_in[6];
    const float* Wv = (const float*)d_in[7];
    const float* bv = (const float*)d_in[8];

    const size_t act = (size_t)ACT_N;
    const size_t wn  = (size_t)W_N;
    __bf16* qx  = (__bf16*)d_ws;
    __bf16* kx  = qx + act;
    __bf16* vx  = kx + act;
    __bf16* wqb = vx + act;
    __bf16* wkb = wqb + wn;
    __bf16* wvb = wkb + wn;
    __bf16* qhd = wvb + wn;
    __bf16* khd = qhd + act;
    __bf16* vhd = khd + act;               // vhd: [bh][64][s] transposed
    float* out = (float*)d_out;

    cvt6<<<dim3(2048, 1, 6), dim3(256), 0, stream>>>(
        q, k, v, Wq, Wk, Wv, qx, kx, vx, wqb, wkb, wvb);
    proj3<<<dim3(32, 8, 3), dim3(256), 0, stream>>>(
        qx, kx, vx, wqb, wkb, wvb, bq, bk, bv, qhd, khd, vhd);
    attn_kernel<<<dim3(512), dim3(256), 0, stream>>>(qhd, khd, vhd, out);
}